// Round 2
// baseline (361.834 us; speedup 1.0000x reference)
//
#include <hip/hip_runtime.h>

// GD_13907104105202: x_K for x <- x - s*(Wx - b), x0=0, K=20, s=1e-6.
// Closed form: x_K = s * sum_{m=0}^{19} C(20,m+1) (-s)^m W^m b.
// m>=2 terms (~3e-12) are below fp32 ulp of the result (~9e-5), so
//   x = 20*s*b - 190*s^2*(W b)
// exactly to fp32 roundoff (round-1: absmax 2.9e-11 vs threshold 1.77e-6).
// One batched matvec: memory-bound on reading W once (268 MB, ~42us @ 6.6 TB/s).
//
// Round-2 change: per-row reduction was 6 dependent ds_bpermute shuffles
// (~120 cyc DS latency each = ~750 serial cyc per 2KB row -> ~2.5 TB/s).
// Now: 4 rows in flight per wave-iteration (8 KB of loads outstanding) and
// DPP-based wave reduction (row_shr 1/2/4/8 + row_bcast 15/31, VALU-speed,
// sum lands in lane 63) + one float4 store per 4 rows.

constexpr int Bsz = 256;
constexpr int N   = 512;
constexpr int BLOCKS_PER_BATCH = 4;
constexpr int ROWS_PER_BLOCK   = N / BLOCKS_PER_BATCH;  // 128
constexpr int THREADS = 256;                             // 4 waves
constexpr int ROWS_PER_WAVE = ROWS_PER_BLOCK / 4;        // 32

template <int CTRL>
__device__ __forceinline__ float dpp_add(float x) {
    // update_dpp(old=0, src, ctrl, row_mask=0xf, bank_mask=0xf, bound_ctrl=1):
    // invalid source lanes contribute 0 -> safe for sum.
    int y = __builtin_amdgcn_update_dpp(0, __float_as_int(x), CTRL, 0xf, 0xf, true);
    return x + __int_as_float(y);
}

// rocPRIM-canonical gfx9 wave64 sum; full sum ends up in lane 63.
__device__ __forceinline__ float wave_reduce_sum(float x) {
    x = dpp_add<0x111>(x);  // row_shr:1
    x = dpp_add<0x112>(x);  // row_shr:2
    x = dpp_add<0x114>(x);  // row_shr:4
    x = dpp_add<0x118>(x);  // row_shr:8  -> lane 15 of each 16-row = row sum
    x = dpp_add<0x142>(x);  // row_bcast:15 -> lane 31 = sum(0..31), lane 63 partial
    x = dpp_add<0x143>(x);  // row_bcast:31 -> lane 63 = sum(0..63)
    return x;
}

__device__ __forceinline__ float dot8(const float4& w0, const float4& w1,
                                      const float4& b0, const float4& b1) {
    return w0.x * b0.x + w0.y * b0.y + w0.z * b0.z + w0.w * b0.w
         + w1.x * b1.x + w1.y * b1.y + w1.z * b1.z + w1.w * b1.w;
}

__global__ __launch_bounds__(THREADS) void gd_closed_form(
    const float* __restrict__ W,     // [B, N, N] row-major
    const float* __restrict__ bv,    // [B, N]
    const float* __restrict__ sptr,  // scalar step size
    float* __restrict__ out)         // [B, N]
{
    __shared__ float sb[N];

    const int batch = blockIdx.x >> 2;   // / BLOCKS_PER_BATCH
    const int slice = blockIdx.x & 3;
    const int row0  = slice * ROWS_PER_BLOCK;

    const float s  = *sptr;
    const float c0 = 20.0f * s;          // coefficient of b
    const float c1 = 190.0f * s * s;     // coefficient of W b

    // Stage b[batch] (512 floats) into LDS: 256 threads x float2.
    const float* bb = bv + (size_t)batch * N;
    ((float2*)sb)[threadIdx.x] = ((const float2*)bb)[threadIdx.x];
    __syncthreads();

    const int wave = threadIdx.x >> 6;
    const int lane = threadIdx.x & 63;

    // Each lane's two b fragments (reused for every row).
    const float4* sb4 = (const float4*)sb;
    const float4 b0 = sb4[lane];        // cols [4*lane, 4*lane+3]
    const float4 b1 = sb4[64 + lane];   // cols [256+4*lane, ...]

    const float4* Wb = (const float4*)(W + (size_t)batch * N * N);
    float* outp = out + (size_t)batch * N;

    // Wave w owns 32 contiguous rows [row0 + 32w, +32), 4 rows per iteration.
    const int rbase = row0 + wave * ROWS_PER_WAVE;

#pragma unroll 2
    for (int it = 0; it < ROWS_PER_WAVE / 4; ++it) {
        const int row = rbase + it * 4;
        const float4* r = Wb + (size_t)row * (N / 4);

        // 8 x global_load_dwordx4 in flight (8 KB/wave/iter).
        const float4 a00 = r[lane],            a01 = r[64 + lane];
        const float4 a10 = r[128 + lane],      a11 = r[192 + lane];
        const float4 a20 = r[256 + lane],      a21 = r[320 + lane];
        const float4 a30 = r[384 + lane],      a31 = r[448 + lane];

        float d0 = dot8(a00, a01, b0, b1);
        float d1 = dot8(a10, a11, b0, b1);
        float d2 = dot8(a20, a21, b0, b1);
        float d3 = dot8(a30, a31, b0, b1);

        // 4 independent VALU-speed DPP chains (pipeline each other).
        d0 = wave_reduce_sum(d0);
        d1 = wave_reduce_sum(d1);
        d2 = wave_reduce_sum(d2);
        d3 = wave_reduce_sum(d3);

        if (lane == 63) {
            const float4 bq = *(const float4*)(sb + row);
            float4 o;
            o.x = c0 * bq.x - c1 * d0;
            o.y = c0 * bq.y - c1 * d1;
            o.z = c0 * bq.z - c1 * d2;
            o.w = c0 * bq.w - c1 * d3;
            *(float4*)(outp + row) = o;  // row % 4 == 0 -> 16B aligned
        }
    }
}

extern "C" void kernel_launch(void* const* d_in, const int* in_sizes, int n_in,
                              void* d_out, int out_size, void* d_ws, size_t ws_size,
                              hipStream_t stream) {
    const float* W  = (const float*)d_in[0];
    const float* bv = (const float*)d_in[1];
    const float* s  = (const float*)d_in[2];
    float* out      = (float*)d_out;

    dim3 grid(Bsz * BLOCKS_PER_BATCH);
    dim3 block(THREADS);
    gd_closed_form<<<grid, block, 0, stream>>>(W, bv, s, out);
}

// Round 3
// 358.751 us; speedup vs baseline: 1.0086x; 1.0086x over previous
//
#include <hip/hip_runtime.h>

// GD_13907104105202: x_K for x <- x - s*(Wx - b), x0=0, K=20, s=1e-6.
// Closed form: x = 20*s*b - 190*s^2*(W b); m>=2 series terms (~3e-12) are
// below fp32 ulp of the result (~9e-5). Verified r1/r2: absmax 2.9e-11.
//
// Round-3 change: DENSE-FRONT access topology. r1/r2 gave each wave a private
// 64-256 KB slice -> 1024-4096 independent DRAM streams -> ~2.4 TB/s.
// Now wave g (of 4096) processes flat row t*4096+g at iteration t: the whole
// grid reads one contiguous ~8 MB band at a time, marching through W like the
// 6.3 TB/s grid-stride copy ubench. Since 4096 % 512 == 0, each wave keeps a
// fixed row-within-batch rib = g & 511 and steps batch by 8 per iteration.
// All loads (W row, b frags, b[rib]) are 1-deep software-pipelined.

constexpr int NB      = 256;                     // batches
constexpr int N       = 512;
constexpr int THREADS = 256;                     // 4 waves/block
constexpr int BLOCKS  = 1024;
constexpr int WAVES   = BLOCKS * (THREADS / 64); // 4096
constexpr int ITERS   = NB * N / WAVES;          // 32 rows per wave
constexpr int BSTEP   = WAVES / N;               // batch step per iter = 8

template <int CTRL>
__device__ __forceinline__ float dpp_add(float x) {
    int y = __builtin_amdgcn_update_dpp(0, __float_as_int(x), CTRL, 0xf, 0xf, true);
    return x + __int_as_float(y);
}

// gfx9 wave64 sum via DPP; full sum lands in lane 63.
__device__ __forceinline__ float wave_reduce_sum(float x) {
    x = dpp_add<0x111>(x);  // row_shr:1
    x = dpp_add<0x112>(x);  // row_shr:2
    x = dpp_add<0x114>(x);  // row_shr:4
    x = dpp_add<0x118>(x);  // row_shr:8
    x = dpp_add<0x142>(x);  // row_bcast:15
    x = dpp_add<0x143>(x);  // row_bcast:31
    return x;
}

__device__ __forceinline__ float dot8(const float4& w0, const float4& w1,
                                      const float4& b0, const float4& b1) {
    return w0.x * b0.x + w0.y * b0.y + w0.z * b0.z + w0.w * b0.w
         + w1.x * b1.x + w1.y * b1.y + w1.z * b1.z + w1.w * b1.w;
}

__global__ __launch_bounds__(THREADS) void gd_dense(
    const float* __restrict__ W,     // [B, N, N] row-major
    const float* __restrict__ bv,    // [B, N]
    const float* __restrict__ sptr,  // scalar step size
    float* __restrict__ out)         // [B, N]
{
    const int wave = threadIdx.x >> 6;
    const int lane = threadIdx.x & 63;
    const int g    = (blockIdx.x << 2) + wave;   // global wave id, 0..4095
    const int rib  = g & (N - 1);                // fixed row-within-batch
    const int bat0 = g >> 9;                     // starting batch, 0..7

    const float s  = *sptr;
    const float c0 = 20.0f * s;
    const float c1 = 190.0f * s * s;

    const float4* W4 = (const float4*)W;
    const float4* B4 = (const float4*)bv;

    size_t wrow = ((size_t)bat0 * N + rib) * (N / 4);  // float4 index of W row
    size_t brow = (size_t)bat0 * (N / 4);              // float4 index of b row
    const size_t WSTEP  = (size_t)BSTEP * N * (N / 4); // advance 8 batches
    const size_t BSTEPW = (size_t)BSTEP * (N / 4);

    // Pipeline stage 0.
    float4 w0  = W4[wrow + lane],      w1  = W4[wrow + 64 + lane];
    float4 bb0 = B4[brow + lane],      bb1 = B4[brow + 64 + lane];
    float  brib = bv[(size_t)bat0 * N + rib];

#pragma unroll 4
    for (int t = 0; t < ITERS - 1; ++t) {
        // Prefetch t+1 (independent of current compute).
        const size_t nw = wrow + WSTEP, nb = brow + BSTEPW;
        float4 pw0 = W4[nw + lane],  pw1 = W4[nw + 64 + lane];
        float4 pb0 = B4[nb + lane],  pb1 = B4[nb + 64 + lane];
        float  pbr = bv[(size_t)(bat0 + BSTEP * (t + 1)) * N + rib];

        float d = wave_reduce_sum(dot8(w0, w1, bb0, bb1));
        if (lane == 63)
            out[(size_t)(bat0 + BSTEP * t) * N + rib] = c0 * brib - c1 * d;

        w0 = pw0; w1 = pw1; bb0 = pb0; bb1 = pb1; brib = pbr;
        wrow = nw; brow = nb;
    }

    float d = wave_reduce_sum(dot8(w0, w1, bb0, bb1));
    if (lane == 63)
        out[(size_t)(bat0 + BSTEP * (ITERS - 1)) * N + rib] = c0 * brib - c1 * d;
}

extern "C" void kernel_launch(void* const* d_in, const int* in_sizes, int n_in,
                              void* d_out, int out_size, void* d_ws, size_t ws_size,
                              hipStream_t stream) {
    const float* W  = (const float*)d_in[0];
    const float* bv = (const float*)d_in[1];
    const float* s  = (const float*)d_in[2];
    float* out      = (float*)d_out;

    gd_dense<<<dim3(BLOCKS), dim3(THREADS), 0, stream>>>(W, bv, s, out);
}